// Round 10
// baseline (762.198 us; speedup 1.0000x reference)
//
#include <hip/hip_runtime.h>
#include <math.h>

// SelfAttention B=4,S=2048,D=1024 fp32. Round 10: r9 ledger -> 2 LDS slots,
// vmcnt(0)+barrier per tile (m97 ledger), >=512-block grids and >=2 blocks/CU
// on every GEMM (m114 overlap covers the drain). Numerics unchanged:
// split-bf16 concat-K (hh+hl+lh) logit chain, validated r2-r9.

typedef unsigned short u16;
typedef __attribute__((ext_vector_type(8))) short bf16x8;
typedef __attribute__((ext_vector_type(4))) float f32x4;

__device__ __forceinline__ u16 f2bf(float x) {
  unsigned u = __float_as_uint(x);
  unsigned r = (u + 0x7fffu + ((u >> 16) & 1u)) >> 16;
  return (u16)r;
}
__device__ __forceinline__ float bf2f(u16 h) {
  return __uint_as_float((unsigned)h << 16);
}

__device__ __forceinline__ void gload_lds16(const u16* g, u16* l) {
  __builtin_amdgcn_global_load_lds(
      (const __attribute__((address_space(1))) unsigned int*)(g),
      (__attribute__((address_space(3))) unsigned int*)(l), 16, 0, 0);
}

// fp32 -> hi bf16 (+ optional lo bf16), grid-stride, vectorized
template <bool LO>
__global__ __launch_bounds__(256) void split_f32_kernel(
    const float* __restrict__ in, u16* __restrict__ hi, u16* __restrict__ lo,
    long long n) {
  long long i = ((long long)blockIdx.x * 256 + threadIdx.x) * 4;
  const long long step = (long long)gridDim.x * 256 * 4;
  for (; i < n; i += step) {
    float4 x = *(const float4*)(in + i);
    float xs[4] = {x.x, x.y, x.z, x.w};
    u16 hv[4], lv[4];
#pragma unroll
    for (int j = 0; j < 4; j++) {
      hv[j] = f2bf(xs[j]);
      if (LO) lv[j] = f2bf(xs[j] - bf2f(hv[j]));
    }
    ushort4 h;
    h.x = hv[0]; h.y = hv[1]; h.z = hv[2]; h.w = hv[3];
    *(ushort4*)(hi + i) = h;
    if (LO) {
      ushort4 l;
      l.x = lv[0]; l.y = lv[1]; l.z = lv[2]; l.w = lv[3];
      *(ushort4*)(lo + i) = l;
    }
  }
}

// NT GEMM over NSEG K-segments. BM=32*M_REP (64/128/256), BN=256, BK=32.
// 512 thr = 8 waves (2M x 4N); per-wave (M_REP*16) x 64 output.
// LDS: 2 slots x (A BM*32 + B 256*32) u16; subtile layout per tile:
//   elem(row,k) at u16 off (row>>4)*512 + ((k>>3)&3)*128 + (row&15)*8 + (k&7)
//   stage chunk c -> row=((c>>6)<<4)+(c&15), k=((c>>4)&3)*8 (linear dest)
//   frag read rowblock rb: rb*512 + lane*8 -> conflict-free ds_read_b128.
// m97 ledger @512thr: compute tile t from slot[t&1] while staging t+1 into
// slot[(t+1)&1] (its reads finished before the barrier at end of t-1);
// end of tile: vmcnt(0) + s_barrier (t+1 landed). Co-resident blocks
// (>=2/CU via small LDS + >=512-block grids) cover the drain (m114).
// STORE: 0 = f32 Cf, 1 = split bf16 (Ch,Cl), 2 = bf16 (Ch).
template <int NSEG, int STORE, int M_REP>
__global__ __launch_bounds__(512, 2) void gemmc(
    const u16* __restrict__ A0, const u16* __restrict__ A1,
    const u16* __restrict__ A2, const u16* __restrict__ B0,
    const u16* __restrict__ B1, const u16* __restrict__ B2,
    float* __restrict__ Cf, u16* __restrict__ Ch, u16* __restrict__ Cl,
    int Kseg, int lda, int ldb, int ldc,
    long long sA, long long sB, long long sC) {
  constexpr int BM = 32 * M_REP;
  constexpr int ASZ = BM * 32;   // u16
  constexpr int BSZ = 8192;      // 256x32 u16
  constexpr int SLOT = ASZ + BSZ;
  constexpr int ACH = ASZ / 8;   // 16B chunks in A tile
  __shared__ u16 lds[2 * SLOT];

  const int tid = threadIdx.x;
  const int ln = tid & 63;
  const int wid = tid >> 6;
  const int wm = wid >> 2;  // 0..1
  const int wn = wid & 3;   // 0..3
  const int m0 = blockIdx.y * BM;
  const int n0 = blockIdx.x * 256;
  const int z = blockIdx.z;
  const long long za = (long long)z * sA;
  const long long zb = (long long)z * sB;

  const int NT = NSEG * (Kseg >> 5);

  f32x4 acc[M_REP][4];
  const f32x4 zero = {0.f, 0.f, 0.f, 0.f};
#pragma unroll
  for (int i = 0; i < M_REP; i++)
#pragma unroll
    for (int j = 0; j < 4; j++) acc[i][j] = zero;

  auto baseA = [&](int t) -> const u16* {
    int kk = t << 5;
    const u16* p = A0;
    if (NSEG >= 2 && kk >= Kseg) { kk -= Kseg; p = A1; }
    if (NSEG >= 3 && kk >= Kseg) { kk -= Kseg; p = A2; }
    return p + za + (size_t)m0 * lda + kk;
  };
  auto baseB = [&](int t) -> const u16* {
    int kk = t << 5;
    const u16* p = B0;
    if (NSEG >= 2 && kk >= Kseg) { kk -= Kseg; p = B1; }
    if (NSEG >= 3 && kk >= Kseg) { kk -= Kseg; p = B2; }
    return p + zb + (size_t)n0 * ldb + kk;
  };
  auto stage = [&](int t) {
    u16* slot = lds + (t & 1) * SLOT;
    const u16* Ab = baseA(t);
    const u16* Bb = baseB(t);
    if constexpr (ACH >= 512) {
#pragma unroll
      for (int l = 0; l < ACH / 512; ++l) {
        const int c = tid + l * 512;
        const int row = ((c >> 6) << 4) + (c & 15);
        const int kk = ((c >> 4) & 3) * 8;
        gload_lds16(Ab + (size_t)row * lda + kk, slot + c * 8);
      }
    } else {
      if (tid < ACH) {
        const int c = tid;
        const int row = ((c >> 6) << 4) + (c & 15);
        const int kk = ((c >> 4) & 3) * 8;
        gload_lds16(Ab + (size_t)row * lda + kk, slot + c * 8);
      }
    }
#pragma unroll
    for (int l = 0; l < 2; ++l) {
      const int c = tid + l * 512;
      const int row = ((c >> 6) << 4) + (c & 15);
      const int kk = ((c >> 4) & 3) * 8;
      gload_lds16(Bb + (size_t)row * ldb + kk, slot + ASZ + c * 8);
    }
  };

  // prologue: tile 0 staged and drained
  stage(0);
  asm volatile("s_waitcnt vmcnt(0)" ::: "memory");
  __builtin_amdgcn_s_barrier();
  __builtin_amdgcn_sched_barrier(0);

  for (int t = 0; t < NT; ++t) {
    if (t + 1 < NT) stage(t + 1);  // -> slot[(t+1)&1], safe per ledger
    const u16* Abuf = lds + (t & 1) * SLOT;
    const u16* Bbuf = Abuf + ASZ;
    const int fo = ln * 8;
    bf16x8 a[M_REP], b[4];
#pragma unroll
    for (int j = 0; j < 4; ++j)
      b[j] = *(const bf16x8*)(Bbuf + (wn * 4 + j) * 512 + fo);
#pragma unroll
    for (int i = 0; i < M_REP; ++i)
      a[i] = *(const bf16x8*)(Abuf + (wm * M_REP + i) * 512 + fo);
#pragma unroll
    for (int i = 0; i < M_REP; ++i)
#pragma unroll
      for (int j = 0; j < 4; ++j)
        acc[i][j] = __builtin_amdgcn_mfma_f32_16x16x32_bf16(
            a[i], b[j], acc[i][j], 0, 0, 0);
    if (t + 1 < NT) {
      asm volatile("s_waitcnt vmcnt(0)" ::: "memory");  // tile t+1 landed
      __builtin_amdgcn_s_barrier();
      __builtin_amdgcn_sched_barrier(0);
    }
  }

  // epilogue: C/D layout col=lane&15, row=(lane>>4)*4+reg (validated r2-r9)
  const int orow = (ln >> 4) * 4;
  const int ocol = ln & 15;
#pragma unroll
  for (int mi = 0; mi < M_REP; ++mi)
#pragma unroll
    for (int ni = 0; ni < 4; ++ni) {
      const int rbase = m0 + wm * (M_REP * 16) + mi * 16 + orow;
      const int cc = n0 + wn * 64 + ni * 16 + ocol;
#pragma unroll
      for (int i = 0; i < 4; ++i) {
        const float v = acc[mi][ni][i];
        const long long off =
            (long long)(rbase + i) * ldc + cc + (long long)z * sC;
        if (STORE == 0) {
          Cf[off] = v;
        } else if (STORE == 1) {
          const u16 h = f2bf(v);
          Ch[off] = h;
          Cl[off] = f2bf(v - bf2f(h));
        } else {
          Ch[off] = f2bf(v);
        }
      }
    }
}

// ---- softmax kernels (row = 2048) ----
__device__ __forceinline__ float blk_max(float v, float* red) {
  const int wv = threadIdx.x >> 6, lnn = threadIdx.x & 63;
#pragma unroll
  for (int off = 32; off; off >>= 1) v = fmaxf(v, __shfl_xor(v, off));
  if (lnn == 0) red[wv] = v;
  __syncthreads();
  return fmaxf(fmaxf(red[0], red[1]), fmaxf(red[2], red[3]));
}
__device__ __forceinline__ float blk_sum(float v, float* red) {
  const int wv = threadIdx.x >> 6, lnn = threadIdx.x & 63;
#pragma unroll
  for (int off = 32; off; off >>= 1) v += __shfl_xor(v, off);
  if (lnn == 0) red[wv] = v;
  __syncthreads();
  return red[0] + red[1] + red[2] + red[3];
}

// f32 L row -> bf16 P in place (row stride stays 4096 u16)
__global__ __launch_bounds__(256) void softmax_inplace(float* __restrict__ L) {
  float* p = L + (size_t)blockIdx.x * 2048;
  const int t = threadIdx.x;
  __shared__ float redm[4];
  __shared__ float reds[4];

  float4 x0 = *(const float4*)(p + t * 4);
  float4 x1 = *(const float4*)(p + 1024 + t * 4);
  float m = fmaxf(fmaxf(fmaxf(x0.x, x0.y), fmaxf(x0.z, x0.w)),
                  fmaxf(fmaxf(x1.x, x1.y), fmaxf(x1.z, x1.w)));
  m = blk_max(m, redm);
  float e[8];
  e[0] = __expf(x0.x - m); e[1] = __expf(x0.y - m);
  e[2] = __expf(x0.z - m); e[3] = __expf(x0.w - m);
  e[4] = __expf(x1.x - m); e[5] = __expf(x1.y - m);
  e[6] = __expf(x1.z - m); e[7] = __expf(x1.w - m);
  float s = e[0] + e[1] + e[2] + e[3] + e[4] + e[5] + e[6] + e[7];
  s = blk_sum(s, reds);
  const float inv = 1.f / s;
  u16* q = (u16*)p;
  ushort4 o0, o1;
  o0.x = f2bf(e[0] * inv); o0.y = f2bf(e[1] * inv);
  o0.z = f2bf(e[2] * inv); o0.w = f2bf(e[3] * inv);
  o1.x = f2bf(e[4] * inv); o1.y = f2bf(e[5] * inv);
  o1.z = f2bf(e[6] * inv); o1.w = f2bf(e[7] * inv);
  *(ushort4*)(q + t * 4) = o0;
  *(ushort4*)(q + 1024 + t * 4) = o1;
}

// split-bf16 L (Lh+Ll, row stride 2048 u16 each) -> bf16 P over Lh row
__global__ __launch_bounds__(256) void softmax_split(
    u16* __restrict__ Lh, const u16* __restrict__ Ll) {
  u16* ph = Lh + (size_t)blockIdx.x * 2048;
  const u16* pl = Ll + (size_t)blockIdx.x * 2048;
  const int t = threadIdx.x;
  __shared__ float redm[4];
  __shared__ float reds[4];

  ushort4 h0 = *(const ushort4*)(ph + t * 4);
  ushort4 h1 = *(const ushort4*)(ph + 1024 + t * 4);
  ushort4 l0 = *(const ushort4*)(pl + t * 4);
  ushort4 l1 = *(const ushort4*)(pl + 1024 + t * 4);
  float x[8];
  x[0] = bf2f(h0.x) + bf2f(l0.x); x[1] = bf2f(h0.y) + bf2f(l0.y);
  x[2] = bf2f(h0.z) + bf2f(l0.z); x[3] = bf2f(h0.w) + bf2f(l0.w);
  x[4] = bf2f(h1.x) + bf2f(l1.x); x[5] = bf2f(h1.y) + bf2f(l1.y);
  x[6] = bf2f(h1.z) + bf2f(l1.z); x[7] = bf2f(h1.w) + bf2f(l1.w);
  float m = fmaxf(fmaxf(fmaxf(x[0], x[1]), fmaxf(x[2], x[3])),
                  fmaxf(fmaxf(x[4], x[5]), fmaxf(x[6], x[7])));
  m = blk_max(m, redm);
  float e[8];
#pragma unroll
  for (int j = 0; j < 8; ++j) e[j] = __expf(x[j] - m);
  float s = e[0] + e[1] + e[2] + e[3] + e[4] + e[5] + e[6] + e[7];
  s = blk_sum(s, reds);
  const float inv = 1.f / s;
  ushort4 o0, o1;
  o0.x = f2bf(e[0] * inv); o0.y = f2bf(e[1] * inv);
  o0.z = f2bf(e[2] * inv); o0.w = f2bf(e[3] * inv);
  o1.x = f2bf(e[4] * inv); o1.y = f2bf(e[5] * inv);
  o1.z = f2bf(e[6] * inv); o1.w = f2bf(e[7] * inv);
  *(ushort4*)(ph + t * 4) = o0;
  *(ushort4*)(ph + 1024 + t * 4) = o1;
}

extern "C" void kernel_launch(void* const* d_in, const int* in_sizes, int n_in,
                              void* d_out, int out_size, void* d_ws, size_t ws_size,
                              hipStream_t stream) {
  constexpr int Bn = 4, S = 2048, D = 1024;
  constexpr long long TOK = (long long)Bn * S;  // 8192
  constexpr long long DD = (long long)D * D;
  const float* X = (const float*)d_in[0];
  const float* Wq = (const float*)d_in[1];
  const float* Wk = (const float*)d_in[2];
  const float* Wv = (const float*)d_in[3];
  float* out = (float*)d_out;
  const dim3 blk(256);
  const dim3 gblk(512);

  char* w = (char*)d_ws;
  auto au16 = [&](long long n) { u16* p = (u16*)w; w += n * 2; return p; };

  // exact byte budgets (base = 127,926,272)
  const bool tA = ws_size >= (size_t)195035136ULL;  // + f32 L (67.1 MB tail)
  const bool tB = ws_size >= (size_t)161480704ULL;  // + Ll bf16 (33.55 tail)
  const bool tC = ws_size >= (size_t)140000000ULL;  // L aliases Xh/Xl, G=2

  if (tA || tB || tC) {
    u16* Xh = au16(TOK * D);
    u16* Xl = au16(TOK * D);
    u16* Wch = au16(2 * DD);  // [Wq;Wk] hi
    u16* Wcl = au16(2 * DD);
    u16* Wvh = au16(DD);
    u16* QKh = au16(TOK * 2 * D);  // cols 0..1023 = Q, 1024..2047 = K
    u16* QKl = au16(TOK * 2 * D);
    u16* VT = au16((long long)D * TOK);  // [1024][8192], col = b*2048+s

    split_f32_kernel<true><<<2048, blk, 0, stream>>>(X, Xh, Xl, TOK * D);
    split_f32_kernel<true><<<512, blk, 0, stream>>>(Wq, Wch, Wcl, DD);
    split_f32_kernel<true><<<512, blk, 0, stream>>>(Wk, Wch + DD, Wcl + DD, DD);
    split_f32_kernel<false><<<512, blk, 0, stream>>>(Wv, Wvh, nullptr, DD);

    // fused Q|K projection: M=8192, N=2048, BM=128 -> (8,64) = 512 blocks
    gemmc<3, 1, 4><<<dim3(8, 64, 1), gblk, 0, stream>>>(
        Xh, Xh, Xl, Wch, Wcl, Wch, nullptr, QKh, QKl,
        D, D, D, 2 * D, 0, 0, 0);
    // VT[e,tok] = Wvh . Xh^T : M=1024, N=8192, BM=64 -> (32,16) = 512 blocks
    gemmc<1, 2, 2><<<dim3(32, 16, 1), gblk, 0, stream>>>(
        Wvh, nullptr, nullptr, Xh, nullptr, nullptr, nullptr, VT, nullptr,
        D, D, D, (int)TOK, 0, 0, 0);
    // X/W buffers are dead from here on (44.03 MB at d_ws offset 0).

    if (tA) {
      float* Lf = (float*)w;  // 4*S*S f32 tail
      // BM=128 -> (8,16,4) = 512 blocks
      gemmc<3, 0, 4><<<dim3(8, 16, 4), gblk, 0, stream>>>(
          QKh, QKh, QKl, QKh + D, QKl + D, QKh + D,
          Lf, nullptr, nullptr, D, 2 * D, 2 * D, S,
          (long long)S * 2 * D, (long long)S * 2 * D, (long long)S * S);
      softmax_inplace<<<dim3(4 * S), blk, 0, stream>>>(Lf);
      // O = P . VT^T : BM=64 -> (4,32,4) = 512 blocks
      gemmc<1, 0, 2><<<dim3(4, 32, 4), gblk, 0, stream>>>(
          (const u16*)Lf, nullptr, nullptr, VT, nullptr, nullptr,
          out, nullptr, nullptr, S, 2 * S, (int)TOK, D,
          (long long)S * S * 2, (long long)S, (long long)S * D);
    } else if (tB) {
      u16* Lh = (u16*)d_ws;   // over dead X/W region (33.55 <= 44.03 MB)
      u16* Ll = au16((long long)Bn * S * S);  // 33.55 MB tail
      gemmc<3, 1, 4><<<dim3(8, 16, 4), gblk, 0, stream>>>(
          QKh, QKh, QKl, QKh + D, QKl + D, QKh + D,
          nullptr, Lh, Ll, D, 2 * D, 2 * D, S,
          (long long)S * 2 * D, (long long)S * 2 * D, (long long)S * S);
      softmax_split<<<dim3(4 * S), blk, 0, stream>>>(Lh, Ll);
      gemmc<1, 0, 2><<<dim3(4, 32, 4), gblk, 0, stream>>>(
          Lh, nullptr, nullptr, VT, nullptr, nullptr,
          out, nullptr, nullptr, S, S, (int)TOK, D,
          (long long)S * S, (long long)S, (long long)S * D);
    } else {
      float* Lf = (float*)d_ws;  // 2 batches over dead X region
      for (int g = 0; g < 2; ++g) {
        const long long ro = (long long)g * 2 * S * 2 * D;
        gemmc<3, 0, 4><<<dim3(8, 16, 2), gblk, 0, stream>>>(
            QKh + ro, QKh + ro, QKl + ro,
            QKh + ro + D, QKl + ro + D, QKh + ro + D,
            Lf, nullptr, nullptr, D, 2 * D, 2 * D, S,
            (long long)S * 2 * D, (long long)S * 2 * D, (long long)S * S);
        softmax_inplace<<<dim3(2 * S), blk, 0, stream>>>(Lf);
        gemmc<1, 0, 2><<<dim3(4, 32, 2), gblk, 0, stream>>>(
            (const u16*)Lf, nullptr, nullptr, VT + (long long)g * 2 * S,
            nullptr, nullptr, out + (long long)g * 2 * S * D, nullptr,
            nullptr, S, 2 * S, (int)TOK, D,
            (long long)S * S * 2, (long long)S, (long long)S * D);
      }
    }
  } else {
    // Low tier (~82 MB): per-batch
    u16* Xh = au16(TOK * D);
    u16* Xl = au16(TOK * D);
    u16* Wch = au16(2 * DD);
    u16* Wcl = au16(2 * DD);
    u16* Wvh = au16(DD);
    u16* QKhb = au16((long long)S * 2 * D);
    u16* QKlb = au16((long long)S * 2 * D);
    u16* VTb = au16((long long)D * S);
    float* Lb = (float*)w;

    split_f32_kernel<true><<<2048, blk, 0, stream>>>(X, Xh, Xl, TOK * D);
    split_f32_kernel<true><<<512, blk, 0, stream>>>(Wq, Wch, Wcl, DD);
    split_f32_kernel<true><<<512, blk, 0, stream>>>(Wk, Wch + DD, Wcl + DD, DD);
    split_f32_kernel<false><<<512, blk, 0, stream>>>(Wv, Wvh, nullptr, DD);

    for (int b = 0; b < Bn; ++b) {
      const long long xo = (long long)b * S * D;
      gemmc<3, 1, 4><<<dim3(8, 16, 1), gblk, 0, stream>>>(
          Xh + xo, Xh + xo, Xl + xo, Wch, Wcl, Wch, nullptr, QKhb, QKlb,
          D, D, D, 2 * D, 0, 0, 0);
      gemmc<1, 2, 2><<<dim3(8, 16, 1), gblk, 0, stream>>>(
          Wvh, nullptr, nullptr, Xh + xo, nullptr, nullptr, nullptr, VTb,
          nullptr, D, D, D, S, 0, 0, 0);
      gemmc<3, 0, 4><<<dim3(8, 16, 1), gblk, 0, stream>>>(
          QKhb, QKhb, QKlb, QKhb + D, QKlb + D, QKhb + D,
          Lb, nullptr, nullptr, D, 2 * D, 2 * D, S, 0, 0, 0);
      softmax_inplace<<<dim3(S), blk, 0, stream>>>(Lb);
      gemmc<1, 0, 2><<<dim3(4, 32, 1), gblk, 0, stream>>>(
          (const u16*)Lb, nullptr, nullptr, VTb, nullptr, nullptr,
          out + xo, nullptr, nullptr, S, 2 * S, S, D, 0, 0, 0);
    }
  }
}

// Round 11
// 478.978 us; speedup vs baseline: 1.5913x; 1.5913x over previous
//
#include <hip/hip_runtime.h>
#include <math.h>

// SelfAttention B=4,S=2048,D=1024 fp32. Round 11: r9 structure + i8 QKT.
//   proj (bf16 split 3-seg, r9 gemmc) -> quantizes Q|K to TWO i8 planes
//   VT   (bf16, r9)       QKT: NEW gemmq, 2-limb i8 (aa + (ab+ba)/128),
//   mfma_i32_16x16x64_i8, BK=64, 3-slot lead-2 counted vmcnt -> split-bf16 L
//   softmax_split -> P bf16 over Lh;  PV (bf16, r9) single z=4 launch.
// Memory fits 127.93MB (known ws >= ~140MB): Lh aliases dead X region.

typedef unsigned short u16;
typedef signed char s8;
typedef __attribute__((ext_vector_type(8))) short bf16x8;
typedef __attribute__((ext_vector_type(4))) float f32x4;
typedef __attribute__((ext_vector_type(4))) int i32x4;

__device__ __forceinline__ u16 f2bf(float x) {
  unsigned u = __float_as_uint(x);
  unsigned r = (u + 0x7fffu + ((u >> 16) & 1u)) >> 16;
  return (u16)r;
}
__device__ __forceinline__ float bf2f(u16 h) {
  return __uint_as_float((unsigned)h << 16);
}
__device__ __forceinline__ int clamp127(int q) {
  return q < -127 ? -127 : (q > 127 ? 127 : q);
}

__device__ __forceinline__ void gload_lds16(const void* g, void* l) {
  __builtin_amdgcn_global_load_lds(
      (const __attribute__((address_space(1))) unsigned int*)(g),
      (__attribute__((address_space(3))) unsigned int*)(l), 16, 0, 0);
}

template <int N>
__device__ __forceinline__ void wait_vmcnt() {
  if constexpr (N == 0) asm volatile("s_waitcnt vmcnt(0)" ::: "memory");
  else if constexpr (N == 3) asm volatile("s_waitcnt vmcnt(3)" ::: "memory");
  else if constexpr (N == 4) asm volatile("s_waitcnt vmcnt(4)" ::: "memory");
}

// fp32 -> hi bf16 (+ optional lo bf16), grid-stride, vectorized
template <bool LO>
__global__ __launch_bounds__(256) void split_f32_kernel(
    const float* __restrict__ in, u16* __restrict__ hi, u16* __restrict__ lo,
    long long n) {
  long long i = ((long long)blockIdx.x * 256 + threadIdx.x) * 4;
  const long long step = (long long)gridDim.x * 256 * 4;
  for (; i < n; i += step) {
    float4 x = *(const float4*)(in + i);
    float xs[4] = {x.x, x.y, x.z, x.w};
    u16 hv[4], lv[4];
#pragma unroll
    for (int j = 0; j < 4; j++) {
      hv[j] = f2bf(xs[j]);
      if (LO) lv[j] = f2bf(xs[j] - bf2f(hv[j]));
    }
    ushort4 h;
    h.x = hv[0]; h.y = hv[1]; h.z = hv[2]; h.w = hv[3];
    *(ushort4*)(hi + i) = h;
    if (LO) {
      ushort4 l;
      l.x = lv[0]; l.y = lv[1]; l.z = lv[2]; l.w = lv[3];
      *(ushort4*)(lo + i) = l;
    }
  }
}

// ===== bf16 GEMM (r9-proven): NT over NSEG segs, BK=32, 3 slots, lead 2,
// counted vmcnt(L). BM=32*M_REP, BN=256, 512 thr = 8 waves (2M x 4N).
// LDS subtile: elem(row,k) u16 off (row>>4)*512+((k>>3)&3)*128+(row&15)*8+(k&7)
// STORE: 0=f32, 1=split bf16, 2=bf16, 3=QUANT 2x i8 planes (Ch,Cl reinterp).
template <int NSEG, int STORE, int M_REP>
__global__ __launch_bounds__(512, 2) void gemmc(
    const u16* __restrict__ A0, const u16* __restrict__ A1,
    const u16* __restrict__ A2, const u16* __restrict__ B0,
    const u16* __restrict__ B1, const u16* __restrict__ B2,
    float* __restrict__ Cf, u16* __restrict__ Ch, u16* __restrict__ Cl,
    int Kseg, int lda, int ldb, int ldc,
    long long sA, long long sB, long long sC) {
  constexpr int BM = 32 * M_REP;
  constexpr int ASZ = BM * 32;   // u16
  constexpr int BSZ = 8192;      // 256x32 u16
  constexpr int SLOT = ASZ + BSZ;
  constexpr int LA = M_REP / 4;  // A gloads/thread/tile (>=1 for M_REP>=4)
  constexpr int L = LA + 2;
  __shared__ u16 lds[3 * SLOT];

  const int tid = threadIdx.x;
  const int ln = tid & 63;
  const int wid = tid >> 6;
  const int wm = wid >> 2;
  const int wn = wid & 3;
  const int m0 = blockIdx.y * BM;
  const int n0 = blockIdx.x * 256;
  const int z = blockIdx.z;
  const long long za = (long long)z * sA;
  const long long zb = (long long)z * sB;

  const int NT = NSEG * (Kseg >> 5);

  f32x4 acc[M_REP][4];
  const f32x4 zero = {0.f, 0.f, 0.f, 0.f};
#pragma unroll
  for (int i = 0; i < M_REP; i++)
#pragma unroll
    for (int j = 0; j < 4; j++) acc[i][j] = zero;

  auto baseA = [&](int t) -> const u16* {
    int kk = t << 5;
    const u16* p = A0;
    if (NSEG >= 2 && kk >= Kseg) { kk -= Kseg; p = A1; }
    if (NSEG >= 3 && kk >= Kseg) { kk -= Kseg; p = A2; }
    return p + za + (size_t)m0 * lda + kk;
  };
  auto baseB = [&](int t) -> const u16* {
    int kk = t << 5;
    const u16* p = B0;
    if (NSEG >= 2 && kk >= Kseg) { kk -= Kseg; p = B1; }
    if (NSEG >= 3 && kk >= Kseg) { kk -= Kseg; p = B2; }
    return p + zb + (size_t)n0 * ldb + kk;
  };
  auto stage = [&](int t) {
    u16* slot = lds + (t % 3) * SLOT;
    const u16* Ab = baseA(t);
    const u16* Bb = baseB(t);
#pragma unroll
    for (int l = 0; l < LA; ++l) {
      const int c = tid + l * 512;
      const int row = ((c >> 6) << 4) + (c & 15);
      const int kk = ((c >> 4) & 3) * 8;
      gload_lds16(Ab + (size_t)row * lda + kk, slot + c * 8);
    }
#pragma unroll
    for (int l = 0; l < 2; ++l) {
      const int c = tid + l * 512;
      const int row = ((c >> 6) << 4) + (c & 15);
      const int kk = ((c >> 4) & 3) * 8;
      gload_lds16(Bb + (size_t)row * ldb + kk, slot + ASZ + c * 8);
    }
  };

  stage(0);
  stage(1);
  wait_vmcnt<L>();
  __builtin_amdgcn_s_barrier();
  __builtin_amdgcn_sched_barrier(0);

  for (int t = 0; t < NT; ++t) {
    if (t + 2 < NT) stage(t + 2);
    const u16* Abuf = lds + (t % 3) * SLOT;
    const u16* Bbuf = Abuf + ASZ;
    const int fo = ln * 8;
    bf16x8 a[M_REP], b[4];
#pragma unroll
    for (int j = 0; j < 4; ++j)
      b[j] = *(const bf16x8*)(Bbuf + (wn * 4 + j) * 512 + fo);
#pragma unroll
    for (int i = 0; i < M_REP; ++i)
      a[i] = *(const bf16x8*)(Abuf + (wm * M_REP + i) * 512 + fo);
    __builtin_amdgcn_s_setprio(1);
#pragma unroll
    for (int i = 0; i < M_REP; ++i)
#pragma unroll
      for (int j = 0; j < 4; ++j)
        acc[i][j] = __builtin_amdgcn_mfma_f32_16x16x32_bf16(
            a[i], b[j], acc[i][j], 0, 0, 0);
    __builtin_amdgcn_s_setprio(0);
    if (t + 1 < NT) {
      if (t + 2 < NT) wait_vmcnt<L>();
      else            wait_vmcnt<0>();
      __builtin_amdgcn_s_barrier();
      __builtin_amdgcn_sched_barrier(0);
    }
  }

  const int orow = (ln >> 4) * 4;
  const int ocol = ln & 15;
#pragma unroll
  for (int mi = 0; mi < M_REP; ++mi)
#pragma unroll
    for (int ni = 0; ni < 4; ++ni) {
      const int rbase = m0 + wm * (M_REP * 16) + mi * 16 + orow;
      const int cc = n0 + wn * 64 + ni * 16 + ocol;
#pragma unroll
      for (int i = 0; i < 4; ++i) {
        const float v = acc[mi][ni][i];
        const long long off =
            (long long)(rbase + i) * ldc + cc + (long long)z * sC;
        if (STORE == 0) {
          Cf[off] = v;
        } else if (STORE == 1) {
          const u16 h = f2bf(v);
          Ch[off] = h;
          Cl[off] = f2bf(v - bf2f(h));
        } else if (STORE == 2) {
          Ch[off] = f2bf(v);
        } else {  // STORE == 3: quantize to 2-limb i8 (x ~ a/16 + b/2048)
          const int qa = clamp127(__float2int_rn(v * 16.f));
          const int qb = clamp127(__float2int_rn((v - qa * 0.0625f) * 2048.f));
          ((s8*)Ch)[off] = (s8)qa;
          ((s8*)Cl)[off] = (s8)qb;
        }
      }
    }
}

// ===== i8 GEMM for QKT: NT, BK=64, BM=128 (M_REP=4), BN=256; 3 segments
// (Qa.Ka->acc0, Qa.Kb->acc1, Qb.Ka->acc1); logit = acc0/256 + acc1/32768.
// LDS subtile (bytes): elem(row,k) at (row>>4)*1024+((k>>4)&3)*256+
// (row&15)*16+(k&15); chunk c -> row=((c>>6)<<4)+(c&15), kk=((c>>4)&3)*16;
// frag: lane ln reads (ln>>4)*256+(ln&15)*16 -> i32x4 (16 i8, conflict-free).
// r9 ledger: 3 slots, lead 2, counted vmcnt(3). STORE: 1=split bf16 (Lh,Ll).
template <int STORE>
__global__ __launch_bounds__(512, 2) void gemmq(
    const s8* __restrict__ A0, const s8* __restrict__ A1,
    const s8* __restrict__ A2, const s8* __restrict__ B0,
    const s8* __restrict__ B1, const s8* __restrict__ B2,
    float* __restrict__ Cf, u16* __restrict__ Ch, u16* __restrict__ Cl,
    int Kseg, int lda, int ldb, int ldc,
    long long sA, long long sB, long long sC) {
  constexpr int ASZ = 128 * 64;  // bytes
  constexpr int BSZ = 256 * 64;  // bytes
  constexpr int SLOT = ASZ + BSZ;
  __shared__ s8 lds[3 * SLOT];

  const int tid = threadIdx.x;
  const int ln = tid & 63;
  const int wid = tid >> 6;
  const int wm = wid >> 2;
  const int wn = wid & 3;
  const int m0 = blockIdx.y * 128;
  const int n0 = blockIdx.x * 256;
  const int z = blockIdx.z;
  const long long za = (long long)z * sA;
  const long long zb = (long long)z * sB;

  const int TPS = Kseg >> 6;  // tiles per segment
  const int NT = 3 * TPS;

  i32x4 accA[4][4], accC[4][4];
  const i32x4 izero = {0, 0, 0, 0};
#pragma unroll
  for (int i = 0; i < 4; i++)
#pragma unroll
    for (int j = 0; j < 4; j++) { accA[i][j] = izero; accC[i][j] = izero; }

  auto baseA = [&](int t) -> const s8* {
    int kk = t << 6;
    const s8* p = A0;
    if (kk >= Kseg) { kk -= Kseg; p = A1; }
    if (kk >= Kseg) { kk -= Kseg; p = A2; }
    return p + za + (size_t)m0 * lda + kk;
  };
  auto baseB = [&](int t) -> const s8* {
    int kk = t << 6;
    const s8* p = B0;
    if (kk >= Kseg) { kk -= Kseg; p = B1; }
    if (kk >= Kseg) { kk -= Kseg; p = B2; }
    return p + zb + (size_t)n0 * ldb + kk;
  };
  auto stage = [&](int t) {
    s8* slot = lds + (t % 3) * SLOT;
    const s8* Ab = baseA(t);
    const s8* Bb = baseB(t);
    {  // A: 512 chunks
      const int c = tid;
      const int row = ((c >> 6) << 4) + (c & 15);
      const int kk = ((c >> 4) & 3) * 16;
      gload_lds16(Ab + (size_t)row * lda + kk, slot + c * 16);
    }
#pragma unroll
    for (int l = 0; l < 2; ++l) {  // B: 1024 chunks
      const int c = tid + l * 512;
      const int row = ((c >> 6) << 4) + (c & 15);
      const int kk = ((c >> 4) & 3) * 16;
      gload_lds16(Bb + (size_t)row * ldb + kk, slot + ASZ + c * 16);
    }
  };

  stage(0);
  stage(1);
  wait_vmcnt<3>();
  __builtin_amdgcn_s_barrier();
  __builtin_amdgcn_sched_barrier(0);

  for (int t = 0; t < NT; ++t) {
    if (t + 2 < NT) stage(t + 2);
    const s8* Abuf = lds + (t % 3) * SLOT;
    const s8* Bbuf = Abuf + ASZ;
    const int fo = (ln >> 4) * 256 + (ln & 15) * 16;
    i32x4 a[4], b[4];
#pragma unroll
    for (int j = 0; j < 4; ++j)
      b[j] = *(const i32x4*)(Bbuf + (wn * 4 + j) * 1024 + fo);
#pragma unroll
    for (int i = 0; i < 4; ++i)
      a[i] = *(const i32x4*)(Abuf + (wm * 4 + i) * 1024 + fo);
    __builtin_amdgcn_s_setprio(1);
    if (t < TPS) {
#pragma unroll
      for (int i = 0; i < 4; ++i)
#pragma unroll
        for (int j = 0; j < 4; ++j)
          accA[i][j] = __builtin_amdgcn_mfma_i32_16x16x64_i8(
              a[i], b[j], accA[i][j], 0, 0, 0);
    } else {
#pragma unroll
      for (int i = 0; i < 4; ++i)
#pragma unroll
        for (int j = 0; j < 4; ++j)
          accC[i][j] = __builtin_amdgcn_mfma_i32_16x16x64_i8(
              a[i], b[j], accC[i][j], 0, 0, 0);
    }
    __builtin_amdgcn_s_setprio(0);
    if (t + 1 < NT) {
      if (t + 2 < NT) wait_vmcnt<3>();
      else            wait_vmcnt<0>();
      __builtin_amdgcn_s_barrier();
      __builtin_amdgcn_sched_barrier(0);
    }
  }

  // epilogue: C/D layout col=lane&15, row=(lane>>4)*4+reg (shape-determined)
  const int orow = (ln >> 4) * 4;
  const int ocol = ln & 15;
#pragma unroll
  for (int mi = 0; mi < 4; ++mi)
#pragma unroll
    for (int ni = 0; ni < 4; ++ni) {
      const int rbase = m0 + wm * 64 + mi * 16 + orow;
      const int cc = n0 + wn * 64 + ni * 16 + ocol;
#pragma unroll
      for (int i = 0; i < 4; ++i) {
        const float v = (float)accA[mi][ni][i] * 0.00390625f +
                        (float)accC[mi][ni][i] * 3.0517578125e-05f;
        const long long off =
            (long long)(rbase + i) * ldc + cc + (long long)z * sC;
        if (STORE == 0) {
          Cf[off] = v;
        } else {
          const u16 h = f2bf(v);
          Ch[off] = h;
          Cl[off] = f2bf(v - bf2f(h));
        }
      }
    }
}

// ---- softmax (row = 2048) ----
__device__ __forceinline__ float blk_max(float v, float* red) {
  const int wv = threadIdx.x >> 6, lnn = threadIdx.x & 63;
#pragma unroll
  for (int off = 32; off; off >>= 1) v = fmaxf(v, __shfl_xor(v, off));
  if (lnn == 0) red[wv] = v;
  __syncthreads();
  return fmaxf(fmaxf(red[0], red[1]), fmaxf(red[2], red[3]));
}
__device__ __forceinline__ float blk_sum(float v, float* red) {
  const int wv = threadIdx.x >> 6, lnn = threadIdx.x & 63;
#pragma unroll
  for (int off = 32; off; off >>= 1) v += __shfl_xor(v, off);
  if (lnn == 0) red[wv] = v;
  __syncthreads();
  return red[0] + red[1] + red[2] + red[3];
}

// f32 L row -> bf16 P in place (row stride stays 4096 u16) [low tier]
__global__ __launch_bounds__(256) void softmax_inplace(float* __restrict__ L) {
  float* p = L + (size_t)blockIdx.x * 2048;
  const int t = threadIdx.x;
  __shared__ float redm[4];
  __shared__ float reds[4];
  float4 x0 = *(const float4*)(p + t * 4);
  float4 x1 = *(const float4*)(p + 1024 + t * 4);
  float m = fmaxf(fmaxf(fmaxf(x0.x, x0.y), fmaxf(x0.z, x0.w)),
                  fmaxf(fmaxf(x1.x, x1.y), fmaxf(x1.z, x1.w)));
  m = blk_max(m, redm);
  float e[8];
  e[0] = __expf(x0.x - m); e[1] = __expf(x0.y - m);
  e[2] = __expf(x0.z - m); e[3] = __expf(x0.w - m);
  e[4] = __expf(x1.x - m); e[5] = __expf(x1.y - m);
  e[6] = __expf(x1.z - m); e[7] = __expf(x1.w - m);
  float s = e[0] + e[1] + e[2] + e[3] + e[4] + e[5] + e[6] + e[7];
  s = blk_sum(s, reds);
  const float inv = 1.f / s;
  u16* q = (u16*)p;
  ushort4 o0, o1;
  o0.x = f2bf(e[0] * inv); o0.y = f2bf(e[1] * inv);
  o0.z = f2bf(e[2] * inv); o0.w = f2bf(e[3] * inv);
  o1.x = f2bf(e[4] * inv); o1.y = f2bf(e[5] * inv);
  o1.z = f2bf(e[6] * inv); o1.w = f2bf(e[7] * inv);
  *(ushort4*)(q + t * 4) = o0;
  *(ushort4*)(q + 1024 + t * 4) = o1;
}

// split-bf16 L (Lh+Ll, row stride 2048 u16 each) -> bf16 P over Lh row
__global__ __launch_bounds__(256) void softmax_split(
    u16* __restrict__ Lh, const u16* __restrict__ Ll) {
  u16* ph = Lh + (size_t)blockIdx.x * 2048;
  const u16* pl = Ll + (size_t)blockIdx.x * 2048;
  const int t = threadIdx.x;
  __shared__ float redm[4];
  __shared__ float reds[4];
  ushort4 h0 = *(const ushort4*)(ph + t * 4);
  ushort4 h1 = *(const ushort4*)(ph + 1024 + t * 4);
  ushort4 l0 = *(const ushort4*)(pl + t * 4);
  ushort4 l1 = *(const ushort4*)(pl + 1024 + t * 4);
  float x[8];
  x[0] = bf2f(h0.x) + bf2f(l0.x); x[1] = bf2f(h0.y) + bf2f(l0.y);
  x[2] = bf2f(h0.z) + bf2f(l0.z); x[3] = bf2f(h0.w) + bf2f(l0.w);
  x[4] = bf2f(h1.x) + bf2f(l1.x); x[5] = bf2f(h1.y) + bf2f(l1.y);
  x[6] = bf2f(h1.z) + bf2f(l1.z); x[7] = bf2f(h1.w) + bf2f(l1.w);
  float m = fmaxf(fmaxf(fmaxf(x[0], x[1]), fmaxf(x[2], x[3])),
                  fmaxf(fmaxf(x[4], x[5]), fmaxf(x[6], x[7])));
  m = blk_max(m, redm);
  float e[8];
#pragma unroll
  for (int j = 0; j < 8; ++j) e[j] = __expf(x[j] - m);
  float s = e[0] + e[1] + e[2] + e[3] + e[4] + e[5] + e[6] + e[7];
  s = blk_sum(s, reds);
  const float inv = 1.f / s;
  ushort4 o0, o1;
  o0.x = f2bf(e[0] * inv); o0.y = f2bf(e[1] * inv);
  o0.z = f2bf(e[2] * inv); o0.w = f2bf(e[3] * inv);
  o1.x = f2bf(e[4] * inv); o1.y = f2bf(e[5] * inv);
  o1.z = f2bf(e[6] * inv); o1.w = f2bf(e[7] * inv);
  *(ushort4*)(ph + t * 4) = o0;
  *(ushort4*)(ph + 1024 + t * 4) = o1;
}

extern "C" void kernel_launch(void* const* d_in, const int* in_sizes, int n_in,
                              void* d_out, int out_size, void* d_ws, size_t ws_size,
                              hipStream_t stream) {
  constexpr int Bn = 4, S = 2048, D = 1024;
  constexpr long long TOK = (long long)Bn * S;  // 8192
  constexpr long long DD = (long long)D * D;
  const float* X = (const float*)d_in[0];
  const float* Wq = (const float*)d_in[1];
  const float* Wk = (const float*)d_in[2];
  const float* Wv = (const float*)d_in[3];
  float* out = (float*)d_out;
  const dim3 blk(256);
  const dim3 gblk(512);

  char* w = (char*)d_ws;
  auto au16 = [&](long long n) { u16* p = (u16*)w; w += n * 2; return p; };
  auto as8 = [&](long long n) { s8* p = (s8*)w; w += n; return p; };

  if (ws_size >= (size_t)127926272ULL) {
    // Layout (127.93 MB): Xh Xl | Wch Wcl Wvh | QKa QKb (i8) | VT | Ll
    u16* Xh = au16(TOK * D);          // dead after VT -> hosts Lh
    u16* Xl = au16(TOK * D);          //   (with Xh: exactly 33,554,432 B)
    u16* Wch = au16(2 * DD);
    u16* Wcl = au16(2 * DD);
    u16* Wvh = au16(DD);
    s8* QKa = as8(TOK * 2 * D);       // i8 hi plane, cols 0..1023=Q, rest=K
    s8* QKb = as8(TOK * 2 * D);       // i8 lo plane
    u16* VT = au16((long long)D * TOK);  // [1024][8192]
    u16* Ll = au16(TOK * S);          // logit lo plane (tail)
    u16* Lh = (u16*)d_ws;             // logit hi plane over dead X region

    split_f32_kernel<true><<<2048, blk, 0, stream>>>(X, Xh, Xl, TOK * D);
    split_f32_kernel<true><<<512, blk, 0, stream>>>(Wq, Wch, Wcl, DD);
    split_f32_kernel<true><<<512, blk, 0, stream>>>(Wk, Wch + DD, Wcl + DD, DD);
    split_f32_kernel<false><<<512, blk, 0, stream>>>(Wv, Wvh, nullptr, DD);

    // fused Q|K projection (split-bf16 3-seg), STORE=3 -> i8 planes
    gemmc<3, 3, 8><<<dim3(8, 32, 1), gblk, 0, stream>>>(
        Xh, Xh, Xl, Wch, Wcl, Wch, nullptr, (u16*)QKa, (u16*)QKb,
        D, D, D, 2 * D, 0, 0, 0);
    // VT[e,tok] = Wvh . Xh^T : (32,8) = 256 blocks
    gemmc<1, 2, 4><<<dim3(32, 8, 1), gblk, 0, stream>>>(
        Wvh, nullptr, nullptr, Xh, nullptr, nullptr, nullptr, VT, nullptr,
        D, D, D, (int)TOK, 0, 0, 0);
    // X region dead now.

    // QKT i8 2-limb, one z=4 launch: (8,16,4) = 512 blocks, 2 blocks/CU
    gemmq<1><<<dim3(8, 16, 4), gblk, 0, stream>>>(
        QKa, QKa, QKb, QKa + D, QKb + D, QKa + D,
        nullptr, Lh, Ll, D, 2 * D, 2 * D, S,
        (long long)S * 2 * D, (long long)S * 2 * D, (long long)S * S);
    softmax_split<<<dim3(4 * S), blk, 0, stream>>>(Lh, Ll);
    // O = P . VT^T : one z=4 launch (4,16,4) = 256 blocks
    gemmc<1, 0, 4><<<dim3(4, 16, 4), gblk, 0, stream>>>(
        Lh, nullptr, nullptr, VT, nullptr, nullptr,
        out, nullptr, nullptr, S, S, (int)TOK, D,
        (long long)S * S, (long long)S, (long long)S * D);
  } else {
    // Low tier (~82 MB): per-batch bf16 path (r9)
    u16* Xh = au16(TOK * D);
    u16* Xl = au16(TOK * D);
    u16* Wch = au16(2 * DD);
    u16* Wcl = au16(2 * DD);
    u16* Wvh = au16(DD);
    u16* QKhb = au16((long long)S * 2 * D);
    u16* QKlb = au16((long long)S * 2 * D);
    u16* VTb = au16((long long)D * S);
    float* Lb = (float*)w;

    split_f32_kernel<true><<<2048, blk, 0, stream>>>(X, Xh, Xl, TOK * D);
    split_f32_kernel<true><<<512, blk, 0, stream>>>(Wq, Wch, Wcl, DD);
    split_f32_kernel<true><<<512, blk, 0, stream>>>(Wk, Wch + DD, Wcl + DD, DD);
    split_f32_kernel<false><<<512, blk, 0, stream>>>(Wv, Wvh, nullptr, DD);

    for (int b = 0; b < Bn; ++b) {
      const long long xo = (long long)b * S * D;
      gemmc<3, 1, 8><<<dim3(8, 8, 1), gblk, 0, stream>>>(
          Xh + xo, Xh + xo, Xl + xo, Wch, Wcl, Wch, nullptr, QKhb, QKlb,
          D, D, D, 2 * D, 0, 0, 0);
      gemmc<1, 2, 4><<<dim3(8, 8, 1), gblk, 0, stream>>>(
          Wvh, nullptr, nullptr, Xh + xo, nullptr, nullptr, nullptr, VTb,
          nullptr, D, D, D, S, 0, 0, 0);
      gemmc<3, 0, 4><<<dim3(8, 16, 1), gblk, 0, stream>>>(
          QKhb, QKhb, QKlb, QKhb + D, QKlb + D, QKhb + D,
          Lb, nullptr, nullptr, D, 2 * D, 2 * D, S, 0, 0, 0);
      softmax_inplace<<<dim3(S), blk, 0, stream>>>(Lb);
      gemmc<1, 0, 4><<<dim3(4, 16, 1), gblk, 0, stream>>>(
          (const u16*)Lb, nullptr, nullptr, VTb, nullptr, nullptr,
          out + xo, nullptr, nullptr, S, 2 * S, S, D, 0, 0, 0);
    }
  }
}